// Round 14
// baseline (206.094 us; speedup 1.0000x reference)
//
#include <hip/hip_runtime.h>

// MHA forward: B=4, S=2048, D=1024, H=16, DK=64.
// out = softmax((xWq+bq)(xWk+bk)^T / 8)(xWv+bv) @ Wo + bo
// All GEMMs in bf16 MFMA (fp32 accum).

typedef unsigned short u16;
typedef unsigned int u32;
typedef __attribute__((ext_vector_type(8))) short bfx8;     // 8 bf16 (4 VGPR) MFMA operand
typedef __attribute__((ext_vector_type(4))) float f32x4;    // 16x16 MFMA accumulator
typedef __attribute__((ext_vector_type(16))) float f32x16;  // 32x32 MFMA accumulator
typedef __attribute__((ext_vector_type(4))) float fx4;
typedef __attribute__((ext_vector_type(8))) u16 u16x8;
typedef __attribute__((ext_vector_type(4))) u16 u16x4;
typedef __attribute__((ext_vector_type(2))) u32 u32x2;
typedef __attribute__((ext_vector_type(4))) u32 u32x4;

__device__ __forceinline__ u16 f2bf(float f) {
  union { float f; u32 u; } v; v.f = f;
  u32 u = v.u;
  u += 0x7fffu + ((u >> 16) & 1u);   // round-to-nearest-even
  return (u16)(u >> 16);
}

__device__ __forceinline__ u32 cvtpk(float a, float b) {
  u32 r;
  asm("v_cvt_pk_bf16_f32 %0, %1, %2" : "=v"(r) : "v"(a), "v"(b));
  return r;
}

// async global->LDS, 16B per lane
__device__ __forceinline__ void gl_lds16(const void* g, void* l) {
  __builtin_amdgcn_global_load_lds((const __attribute__((address_space(1))) void*)g,
                                   (__attribute__((address_space(3))) void*)l, 16, 0, 0);
}

// ---------------- weight transpose: W[1024][1024] fp32 -> Wt[1024][1024] bf16 ----------------
__global__ void wtrans4(const float* __restrict__ W0, const float* __restrict__ W1,
                        const float* __restrict__ W2, const float* __restrict__ W3,
                        u16* __restrict__ WtBase) {
  __shared__ float tile[64][65];
  const int z = blockIdx.z;
  const float* W = z == 0 ? W0 : (z == 1 ? W1 : (z == 2 ? W2 : W3));
  u16* Wt = WtBase + (size_t)z * (1024ull * 1024);
  const int t = threadIdx.x;
  const int n0 = blockIdx.x << 6, k0 = blockIdx.y << 6;
  {
    int r = t >> 2, c = (t & 3) << 4;
    const float* src = W + (size_t)(k0 + r) * 1024 + n0 + c;
#pragma unroll
    for (int u = 0; u < 4; ++u) {
      fx4 vv = *(const fx4*)(src + u * 4);
      tile[r][c + u * 4 + 0] = vv[0];
      tile[r][c + u * 4 + 1] = vv[1];
      tile[r][c + u * 4 + 2] = vv[2];
      tile[r][c + u * 4 + 3] = vv[3];
    }
  }
  __syncthreads();
  {
    int nn = t >> 2, j = t & 3;
    u16x8 o0, o1;
#pragma unroll
    for (int e = 0; e < 8; ++e) o0[e] = f2bf(tile[(j << 4) + e][nn]);
#pragma unroll
    for (int e = 0; e < 8; ++e) o1[e] = f2bf(tile[(j << 4) + 8 + e][nn]);
    u16* dst = Wt + (size_t)(n0 + nn) * 1024 + k0 + (j << 4);
    *(u16x8*)dst = o0;
    *(u16x8*)(dst + 8) = o1;
  }
}

// XCD panel grouping (bijective)
__device__ __forceinline__ void xcd_remap(int& m0, int& n0) {
  const int lin = blockIdx.x + (blockIdx.y << 3);
  const int c = lin & 7, j = lin >> 3;
  m0 = (((j & 7) << 3) + c) << 7;
  n0 = (j >> 3) << 7;
}

// ---------------- QKV GEMM with fused fp32->bf16 A-staging (cvt round-trip deleted) ----------
// A fp32 [8192][1024]; Bt bf16 [1024][1024] (W^T). 128x128 tile, BK=64, 2-phase dbuf.
// Per iter: issue 8x global_load_dwordx4 fp32 A(t+1) + 4x gl_lds B(t+1) BEFORE
// compute(t); after compute, vmcnt waits only for A regs (B stays in flight), then
// cvt_pk -> ds_write_b64 into the swizzled layout; one __syncthreads per iter.
// EPI 0: bf16 head-split; EPI 2: Vt[pair][d][s] direct (vtrans folded).
__global__ void __launch_bounds__(256, 2)
gemm_qkvf(const float* __restrict__ qf32, const float* __restrict__ kf32,
          const float* __restrict__ vf32, const u16* __restrict__ Wt0,
          const float* __restrict__ bq, const float* __restrict__ bk,
          const float* __restrict__ bv, u16* __restrict__ out0, u16* __restrict__ vt) {
  __shared__ __align__(16) char smem[65536];
  const int z = blockIdx.z;
  int m0, n0;
  xcd_remap(m0, n0);
  const float* A = z == 0 ? qf32 : (z == 1 ? kf32 : vf32);
  const u16* Bt = Wt0 + (size_t)z * (1024ull * 1024);
  const float* bias = z == 0 ? bq : (z == 1 ? bk : bv);
  const float scale = z == 0 ? 0.18033688011112042f : 1.0f;  // 0.125*log2(e) into Q

  const int t = threadIdx.x;
  const int w = t >> 6, l = t & 63;
  const int lg = l >> 4, lr = l & 15;
  const int wr = w >> 1, wc = w & 1;

  f32x4 acc[4][4] = {};

  // ---- A staging geometry (fp32 -> bf16 reg-staged) ----
  const int arow = t >> 4;     // 0..15 (+16 per pass)
  const int acol = t & 15;     // 16B fp32 chunk (4 floats = 8B bf16)
  const float* gAf = A + (size_t)(m0 + arow) * 1024 + (acol << 2);
  // write: chunk acol -> slot16 (acol>>1)^(row&7), sub-byte (acol&1)*8; row&7 == arow&7
  const int woff = ((((acol >> 1) ^ (arow & 7)) << 4) + ((acol & 1) << 3));

  // ---- B staging geometry (bf16 gl_lds, proven) ----
  const int trow = t >> 3;
  const int scb = ((t & 7) << 4) ^ ((trow & 7) << 4);
  const char* gB = (const char*)Bt + (size_t)(n0 + trow) * 2048;

  fx4 areg[8];

#define ALOAD(kt)                                                              \
  do {                                                                         \
    _Pragma("unroll")                                                          \
    for (int p = 0; p < 8; ++p)                                                \
      areg[p] = *(const fx4*)(gAf + (size_t)p * 16 * 1024 + ((kt) << 6));      \
  } while (0)

#define AWRITE(buf)                                                            \
  do {                                                                         \
    _Pragma("unroll")                                                          \
    for (int p = 0; p < 8; ++p) {                                              \
      u32x2 pk2;                                                               \
      pk2[0] = cvtpk(areg[p][0], areg[p][1]);                                  \
      pk2[1] = cvtpk(areg[p][2], areg[p][3]);                                  \
      *(u32x2*)((buf) + (((p << 4) + arow) << 7) + woff) = pk2;                \
    }                                                                          \
  } while (0)

#define BSTAGE(kt, buf)                                                        \
  do {                                                                         \
    _Pragma("unroll")                                                          \
    for (int i = 0; i < 4; ++i)                                                \
      gl_lds16(gB + (size_t)i * 32 * 2048 + ((kt) << 7) + scb,                 \
               (buf) + 16384 + (((i << 8) + (w << 6)) << 4));                  \
  } while (0)

  // prologue: stage tile 0
  ALOAD(0);
  BSTAGE(0, smem);
  AWRITE(smem);
  __syncthreads();

  for (int kt = 0; kt < 16; ++kt) {
    char* sA = smem + ((kt & 1) << 15);
    char* sB = sA + 16384;
    char* nb = smem + (((kt + 1) & 1) << 15);
    if (kt < 15) { ALOAD(kt + 1); BSTAGE(kt + 1, nb); }

#pragma unroll
    for (int kk = 0; kk < 2; ++kk) {
      const int off = ((kk << 6) + (lg << 4)) ^ ((lr & 7) << 4);
      bfx8 av[4], bv4[4];
#pragma unroll
      for (int fi = 0; fi < 4; ++fi)
        av[fi] = *(const bfx8*)(sA + ((wr << 6) + (fi << 4) + lr) * 128 + off);
#pragma unroll
      for (int fj = 0; fj < 4; ++fj)
        bv4[fj] = *(const bfx8*)(sB + ((wc << 6) + (fj << 4) + lr) * 128 + off);
#pragma unroll
      for (int fi = 0; fi < 4; ++fi)
#pragma unroll
        for (int fj = 0; fj < 4; ++fj)
          acc[fi][fj] = __builtin_amdgcn_mfma_f32_16x16x32_bf16(av[fi], bv4[fj], acc[fi][fj], 0, 0, 0);
    }
    if (kt < 15) AWRITE(nb);   // compiler waits vmcnt for areg only (B gl_lds stays in flight)
    __syncthreads();           // drains B stage + makes ds_writes visible
  }
#undef ALOAD
#undef AWRITE
#undef BSTAGE

  // ---- epilogue ----
#pragma unroll
  for (int fj = 0; fj < 4; ++fj) {
    const int n = n0 + (wc << 6) + (fj << 4) + lr;
    const float bvl = bias[n];
#pragma unroll
    for (int fi = 0; fi < 4; ++fi) {
      if (z == 2) {
        const int h = n >> 6, d = n & 63;
        const int mm = m0 + (wr << 6) + (fi << 4) + (lg << 2);
        const int b = mm >> 11, s = mm & 2047;
        u16x4 pk4;
#pragma unroll
        for (int r = 0; r < 4; ++r) pk4[r] = f2bf(acc[fi][fj][r] + bvl);
        *(u16x4*)(vt + (size_t)(b * 16 + h) * 131072 + (size_t)d * 2048 + s) = pk4;
      } else {
#pragma unroll
        for (int r = 0; r < 4; ++r) {
          const int m = m0 + (wr << 6) + (fi << 4) + (lg << 2) + r;
          const float val = (acc[fi][fj][r] + bvl) * scale;
          const int b = m >> 11, s = m & 2047, h = n >> 6, d = n & 63;
          out0[(size_t)z * (8192ull * 1024) +
               (((size_t)(b * 16 + h) * 2048 + s) << 6) + d] = f2bf(val);
        }
      }
    }
  }
}

// ---------------- O-projection GEMM (bf16 A via gl_lds, 2-phase dbuf — proven) ----------------
__global__ void __launch_bounds__(256, 2)
gemm_o(const u16* __restrict__ A, const u16* __restrict__ Bt,
       const float* __restrict__ bias, float* __restrict__ out) {
  __shared__ __align__(16) char smem[65536];
  int m0, n0;
  xcd_remap(m0, n0);
  const int t = threadIdx.x;
  const int w = t >> 6, l = t & 63;
  const int lg = l >> 4, lr = l & 15;
  const int wr = w >> 1, wc = w & 1;

  f32x4 acc[4][4] = {};

  const int trow = t >> 3;
  const int scb = ((t & 7) << 4) ^ ((trow & 7) << 4);
  const char* gA = (const char*)A + (size_t)(m0 + trow) * 2048;
  const char* gB = (const char*)Bt + (size_t)(n0 + trow) * 2048;

#define GSTAGE(kt, buf)                                                        \
  do {                                                                         \
    _Pragma("unroll")                                                          \
    for (int i = 0; i < 4; ++i) {                                              \
      gl_lds16(gA + (size_t)i * 32 * 2048 + ((kt) << 7) + scb,                 \
               (buf) + (((i << 8) + (w << 6)) << 4));                          \
      gl_lds16(gB + (size_t)i * 32 * 2048 + ((kt) << 7) + scb,                 \
               (buf) + 16384 + (((i << 8) + (w << 6)) << 4));                  \
    }                                                                          \
  } while (0)

  GSTAGE(0, smem);
  __syncthreads();

  for (int kt = 0; kt < 16; ++kt) {
    char* sA = smem + ((kt & 1) << 15);
    char* sB = sA + 16384;
    if (kt < 15) GSTAGE(kt + 1, smem + (((kt + 1) & 1) << 15));

#pragma unroll
    for (int kk = 0; kk < 2; ++kk) {
      const int off = ((kk << 6) + (lg << 4)) ^ ((lr & 7) << 4);
      bfx8 av[4], bv4[4];
#pragma unroll
      for (int fi = 0; fi < 4; ++fi)
        av[fi] = *(const bfx8*)(sA + ((wr << 6) + (fi << 4) + lr) * 128 + off);
#pragma unroll
      for (int fj = 0; fj < 4; ++fj)
        bv4[fj] = *(const bfx8*)(sB + ((wc << 6) + (fj << 4) + lr) * 128 + off);
#pragma unroll
      for (int fi = 0; fi < 4; ++fi)
#pragma unroll
        for (int fj = 0; fj < 4; ++fj)
          acc[fi][fj] = __builtin_amdgcn_mfma_f32_16x16x32_bf16(av[fi], bv4[fj], acc[fi][fj], 0, 0, 0);
    }
    __syncthreads();
  }
#undef GSTAGE

#pragma unroll
  for (int fj = 0; fj < 4; ++fj) {
    const int n = n0 + (wc << 6) + (fj << 4) + lr;
    const float bvl = bias[n];
#pragma unroll
    for (int fi = 0; fi < 4; ++fi) {
#pragma unroll
      for (int r = 0; r < 4; ++r) {
        const int m = m0 + (wr << 6) + (fi << 4) + (lg << 2) + r;
        out[((size_t)m << 10) + n] = acc[fi][fj][r] + bvl;
      }
    }
  }
}

// ---------------- Flash attention (round-8/9 proven best: 76.6 µs) ----------------
// 32x32 MFMA, in-register P (cvt_pk + permlane32_swap), no-max softmax,
// 4 staging buffers, 2-tile super-iter, 512 thr = 8 waves x 32 q-rows.
__global__ void __launch_bounds__(512, 4)
attn_fwd(const u16* __restrict__ Qg, const u16* __restrict__ Kg,
         const u16* __restrict__ Vtg, u16* __restrict__ Og) {
  __shared__ __align__(16) char smem[65536];
  const int t = threadIdx.x;
  const int w = t >> 6, l = t & 63;
  const int l31 = l & 31, hi = l >> 5;

  const int id = blockIdx.x;               // 512 blocks
  const int xcd = id & 7, slot = id >> 3;  // slot 0..63
  const int pair = ((slot >> 3) << 3) + xcd;
  const int q0 = (slot & 7) << 8;

  const char* Qb = (const char*)Qg + ((size_t)pair << 18);
  const char* Kb = (const char*)Kg + ((size_t)pair << 18);
  const char* Vb = (const char*)Vtg + ((size_t)pair << 18);

  const int trow = t >> 3;
  const int scb = (((t & 7) ^ (trow & 7) ^ (((trow >> 3) & 3) << 1)) << 4);
  const int ldst = (w << 10);
  const int swz = (((l & 7) ^ ((l31 >> 3) << 1)) << 4);

  bfx8 qf[4];
#pragma unroll
  for (int ks = 0; ks < 4; ++ks)
    qf[ks] = *(const bfx8*)(Qb + (size_t)(q0 + (w << 5) + l31) * 128 + (ks << 5) + (hi << 4));

  f32x16 accO[2] = {};
  float Lp = 0.f;

#define ASTAGE(kt, buf)                                                         \
  do {                                                                          \
    gl_lds16(Kb + (size_t)(kt) * 8192 + (size_t)trow * 128 + scb, (buf) + ldst);\
    gl_lds16(Vb + (size_t)trow * 4096 + (size_t)(kt) * 128 + scb,               \
             (buf) + 8192 + ldst);                                              \
  } while (0)

  ASTAGE(0, smem);
  ASTAGE(1, smem + 16384);
  __syncthreads();

  for (int it2 = 0; it2 < 16; ++it2) {
    const int tt = it2 << 1;
    if (tt + 2 < 32) ASTAGE(tt + 2, smem + (((tt + 2) & 3) << 14));
    if (tt + 3 < 32) ASTAGE(tt + 3, smem + (((tt + 3) & 3) << 14));

#pragma unroll
    for (int u = 0; u < 2; ++u) {
      char* bK = smem + (((tt + u) & 3) << 14);
      char* bV = bK + 8192;

      f32x16 accS[2] = {{}, {}};
      __builtin_amdgcn_s_setprio(1);
#pragma unroll
      for (int mb = 0; mb < 2; ++mb) {
        bfx8 kf[4];
#pragma unroll
        for (int ks = 0; ks < 4; ++ks)
          kf[ks] = *(const bfx8*)(bK + (((mb << 5) + l31) << 7) + (((ks << 5) + (hi << 4)) ^ swz));
#pragma unroll
        for (int ks = 0; ks < 4; ++ks)
          accS[mb] = __builtin_amdgcn_mfma_f32_32x32x16_bf16(kf[ks], qf[ks], accS[mb], 0, 0, 0);
      }
      __builtin_amdgcn_s_setprio(0);

      bfx8 pa[4];
#pragma unroll
      for (int mb = 0; mb < 2; ++mb) {
#pragma unroll
        for (int r = 0; r < 16; ++r) {
          accS[mb][r] = __builtin_amdgcn_exp2f(accS[mb][r]);
          Lp += accS[mb][r];
        }
#pragma unroll
        for (int half = 0; half < 2; ++half) {
          u32 a0 = cvtpk(accS[mb][8 * half + 0], accS[mb][8 * half + 1]);
          u32 a1 = cvtpk(accS[mb][8 * half + 2], accS[mb][8 * half + 3]);
          u32 b0 = cvtpk(accS[mb][8 * half + 4], accS[mb][8 * half + 5]);
          u32 b1 = cvtpk(accS[mb][8 * half + 6], accS[mb][8 * half + 7]);
          asm volatile("v_permlane32_swap_b32 %0, %1" : "+v"(a0), "+v"(b0));
          asm volatile("v_permlane32_swap_b32 %0, %1" : "+v"(a1), "+v"(b1));
          u32x4 pk; pk[0] = a0; pk[1] = a1; pk[2] = b0; pk[3] = b1;
          pa[(mb << 1) + half] = *(bfx8*)&pk;
        }
      }

      __builtin_amdgcn_s_setprio(1);
#pragma unroll
      for (int ks = 0; ks < 4; ++ks) {
        bfx8 vf0 = *(const bfx8*)(bV + ((0 + l31) << 7) + (((ks << 5) + (hi << 4)) ^ swz));
        bfx8 vf1 = *(const bfx8*)(bV + ((32 + l31) << 7) + (((ks << 5) + (hi << 4)) ^ swz));
        accO[0] = __builtin_amdgcn_mfma_f32_32x32x16_bf16(pa[ks], vf0, accO[0], 0, 0, 0);
        accO[1] = __builtin_amdgcn_mfma_f32_32x32x16_bf16(pa[ks], vf1, accO[1], 0, 0, 0);
      }
      __builtin_amdgcn_s_setprio(0);
    }

    __syncthreads();
  }
#undef ASTAGE

  const float Ltot = Lp + __shfl_xor(Lp, 32);
  const int b = pair >> 4, h = pair & 15;
  u16* dstBase = Og + (((size_t)(b * 2048 + q0 + (w << 5))) << 10) + (h << 6) + l31;
#pragma unroll
  for (int r = 0; r < 16; ++r) {
    const int ql = (r & 3) + ((r >> 2) << 3) + (hi << 2);
    const float Lr = __shfl(Ltot, ql);
    const float rinv = __builtin_amdgcn_rcpf(Lr);
    u16* dst = dstBase + ((size_t)ql << 10);
    dst[0]  = f2bf(accO[0][r] * rinv);
    dst[32] = f2bf(accO[1][r] * rinv);
  }
}

extern "C" void kernel_launch(void* const* d_in, const int* in_sizes, int n_in,
                              void* d_out, int out_size, void* d_ws, size_t ws_size,
                              hipStream_t stream) {
  const float* q  = (const float*)d_in[0];
  const float* k  = (const float*)d_in[1];
  const float* v  = (const float*)d_in[2];
  const float* Wq = (const float*)d_in[3];
  const float* bq = (const float*)d_in[4];
  const float* Wk = (const float*)d_in[5];
  const float* bk = (const float*)d_in[6];
  const float* Wv = (const float*)d_in[7];
  const float* bv = (const float*)d_in[8];
  const float* Wo = (const float*)d_in[9];
  const float* bo = (const float*)d_in[10];
  float* out = (float*)d_out;
  char* ws = (char*)d_ws;

  const size_t MB = 1024 * 1024;
  if (ws_size < 104 * MB) return;

  u16* Ob  = (u16*)(ws + 0 * MB);    // attention output [8192][1024] bf16
  u16* wqt = (u16*)(ws + 48 * MB);   // [4x contiguous 2MB: Wq^T, Wk^T, Wv^T, Wo^T]
  u16* wot = (u16*)(ws + 54 * MB);
  u16* Qh  = (u16*)(ws + 56 * MB);   // Qh @56, Kh @72 (z-strided)
  u16* Kh  = (u16*)(ws + 72 * MB);
  u16* Vth = (u16*)(ws + 88 * MB);   // Vt[pair][64][2048] written directly by z==2

  wtrans4<<<dim3(16, 16, 4), 256, 0, stream>>>(Wq, Wk, Wv, Wo, wqt);
  gemm_qkvf<<<dim3(8, 64, 3), 256, 0, stream>>>(q, k, v, wqt, bq, bk, bv, Qh, Vth);
  attn_fwd<<<512, 512, 0, stream>>>(Qh, Kh, Vth, Ob);
  gemm_o<<<dim3(8, 64), 256, 0, stream>>>(Ob, wot, bo, out);
}

// Round 15
// 184.445 us; speedup vs baseline: 1.1174x; 1.1174x over previous
//
#include <hip/hip_runtime.h>

// MHA forward: B=4, S=2048, D=1024, H=16, DK=64.
// out = softmax((xWq+bq)(xWk+bk)^T / 8)(xWv+bv) @ Wo + bo
// All GEMMs in bf16 MFMA (fp32 accum).

typedef unsigned short u16;
typedef unsigned int u32;
typedef __attribute__((ext_vector_type(8))) short bfx8;     // 8 bf16 (4 VGPR) MFMA operand
typedef __attribute__((ext_vector_type(4))) float f32x4;    // 16x16 MFMA accumulator
typedef __attribute__((ext_vector_type(16))) float f32x16;  // 32x32 MFMA accumulator
typedef __attribute__((ext_vector_type(4))) float fx4;
typedef __attribute__((ext_vector_type(8))) u16 u16x8;
typedef __attribute__((ext_vector_type(4))) u16 u16x4;
typedef __attribute__((ext_vector_type(2))) u32 u32x2;
typedef __attribute__((ext_vector_type(4))) u32 u32x4;

__device__ __forceinline__ u16 f2bf(float f) {
  union { float f; u32 u; } v; v.f = f;
  u32 u = v.u;
  u += 0x7fffu + ((u >> 16) & 1u);   // round-to-nearest-even
  return (u16)(u >> 16);
}

__device__ __forceinline__ u32 cvtpk(float a, float b) {
  u32 r;
  asm("v_cvt_pk_bf16_f32 %0, %1, %2" : "=v"(r) : "v"(a), "v"(b));
  return r;
}

// async global->LDS, 16B per lane
__device__ __forceinline__ void gl_lds16(const void* g, void* l) {
  __builtin_amdgcn_global_load_lds((const __attribute__((address_space(1))) void*)g,
                                   (__attribute__((address_space(3))) void*)l, 16, 0, 0);
}

// ---------------- weight transpose: W[1024][1024] fp32 -> Wt[1024][1024] bf16 ----------------
__global__ void wtrans4(const float* __restrict__ W0, const float* __restrict__ W1,
                        const float* __restrict__ W2, const float* __restrict__ W3,
                        u16* __restrict__ WtBase) {
  __shared__ float tile[64][65];
  const int z = blockIdx.z;
  const float* W = z == 0 ? W0 : (z == 1 ? W1 : (z == 2 ? W2 : W3));
  u16* Wt = WtBase + (size_t)z * (1024ull * 1024);
  const int t = threadIdx.x;
  const int n0 = blockIdx.x << 6, k0 = blockIdx.y << 6;
  {
    int r = t >> 2, c = (t & 3) << 4;
    const float* src = W + (size_t)(k0 + r) * 1024 + n0 + c;
#pragma unroll
    for (int u = 0; u < 4; ++u) {
      fx4 vv = *(const fx4*)(src + u * 4);
      tile[r][c + u * 4 + 0] = vv[0];
      tile[r][c + u * 4 + 1] = vv[1];
      tile[r][c + u * 4 + 2] = vv[2];
      tile[r][c + u * 4 + 3] = vv[3];
    }
  }
  __syncthreads();
  {
    int nn = t >> 2, j = t & 3;
    u16x8 o0, o1;
#pragma unroll
    for (int e = 0; e < 8; ++e) o0[e] = f2bf(tile[(j << 4) + e][nn]);
#pragma unroll
    for (int e = 0; e < 8; ++e) o1[e] = f2bf(tile[(j << 4) + 8 + e][nn]);
    u16* dst = Wt + (size_t)(n0 + nn) * 1024 + k0 + (j << 4);
    *(u16x8*)dst = o0;
    *(u16x8*)(dst + 8) = o1;
  }
}

// XCD panel grouping (bijective)
__device__ __forceinline__ void xcd_remap(int& m0, int& n0) {
  const int lin = blockIdx.x + (blockIdx.y << 3);
  const int c = lin & 7, j = lin >> 3;
  m0 = (((j & 7) << 3) + c) << 7;
  n0 = (j >> 3) << 7;
}

// ---------------- QKV GEMM, fused fp32->bf16 A-staging, 2-AHEAD pipeline ----------------
// A fp32 [8192][1024]; Bt bf16 [1024][1024]. 128x128 tile, BK=64, 2-phase LDS dbuf.
// Iter kt: BSTAGE(kt+1) -> AWRITE(kt+1) [areg loaded at iter kt-1: full-iteration
// load->use distance, vmcnt wait ~0] -> ALOAD(kt+2) -> MFMA(kt) -> barrier.
// sched_barrier(0) pins each seam so the allocator/scheduler cannot collapse the
// pipeline (round-14 failure mode: wait adjacent to load, 154 us).
__global__ void __launch_bounds__(256, 2)
gemm_qkvf(const float* __restrict__ qf32, const float* __restrict__ kf32,
          const float* __restrict__ vf32, const u16* __restrict__ Wt0,
          const float* __restrict__ bq, const float* __restrict__ bk,
          const float* __restrict__ bv, u16* __restrict__ out0, u16* __restrict__ vt) {
  __shared__ __align__(16) char smem[65536];
  const int z = blockIdx.z;
  int m0, n0;
  xcd_remap(m0, n0);
  const float* A = z == 0 ? qf32 : (z == 1 ? kf32 : vf32);
  const u16* Bt = Wt0 + (size_t)z * (1024ull * 1024);
  const float* bias = z == 0 ? bq : (z == 1 ? bk : bv);
  const float scale = z == 0 ? 0.18033688011112042f : 1.0f;  // 0.125*log2(e) into Q

  const int t = threadIdx.x;
  const int w = t >> 6, l = t & 63;
  const int lg = l >> 4, lr = l & 15;
  const int wr = w >> 1, wc = w & 1;

  f32x4 acc[4][4] = {};

  // ---- A staging geometry (fp32 reg-staged; bf16 chunk c=acol>>1 -> slot c^(row&7)) ----
  const int arow = t >> 4;     // 0..15 (+16 per p)
  const int acol = t & 15;     // 16B fp32 chunk
  const float* gAf = A + (size_t)(m0 + arow) * 1024 + (acol << 2);
  const int woff = ((((acol >> 1) ^ (arow & 7)) << 4) + ((acol & 1) << 3));

  // ---- B staging geometry (bf16 gl_lds, proven) ----
  const int trow = t >> 3;
  const int scb = ((t & 7) << 4) ^ ((trow & 7) << 4);
  const char* gB = (const char*)Bt + (size_t)(n0 + trow) * 2048;

  fx4 areg[8];

#define ALOAD(kt)                                                              \
  do {                                                                         \
    _Pragma("unroll")                                                          \
    for (int p = 0; p < 8; ++p)                                                \
      areg[p] = *(const fx4*)(gAf + (size_t)p * 16 * 1024 + ((kt) << 6));      \
  } while (0)

#define AWRITE(buf)                                                            \
  do {                                                                         \
    _Pragma("unroll")                                                          \
    for (int p = 0; p < 8; ++p) {                                              \
      u32x2 pk2;                                                               \
      pk2[0] = cvtpk(areg[p][0], areg[p][1]);                                  \
      pk2[1] = cvtpk(areg[p][2], areg[p][3]);                                  \
      *(u32x2*)((buf) + (((p << 4) + arow) << 7) + woff) = pk2;                \
    }                                                                          \
  } while (0)

#define BSTAGE(kt, buf)                                                        \
  do {                                                                         \
    _Pragma("unroll")                                                          \
    for (int i = 0; i < 4; ++i)                                                \
      gl_lds16(gB + (size_t)i * 32 * 2048 + ((kt) << 7) + scb,                 \
               (buf) + 16384 + (((i << 8) + (w << 6)) << 4));                  \
  } while (0)

  // prologue: tile 0 staged (one-time serialized A wait), tile 1 A-loads in flight
  ALOAD(0);
  BSTAGE(0, smem);
  AWRITE(smem);
  ALOAD(1);
  __syncthreads();

  for (int kt = 0; kt < 16; ++kt) {
    char* sA = smem + ((kt & 1) << 15);
    char* sB = sA + 16384;
    char* nb = smem + (((kt + 1) & 1) << 15);

    if (kt < 15) {
      BSTAGE(kt + 1, nb);
      __builtin_amdgcn_sched_barrier(0);
      AWRITE(nb);                         // areg = tile kt+1, loaded at iter kt-1
      __builtin_amdgcn_sched_barrier(0);
    }
    if (kt < 14) ALOAD(kt + 2);
    __builtin_amdgcn_sched_barrier(0);

#pragma unroll
    for (int kk = 0; kk < 2; ++kk) {
      const int off = ((kk << 6) + (lg << 4)) ^ ((lr & 7) << 4);
      bfx8 av[4], bv4[4];
#pragma unroll
      for (int fi = 0; fi < 4; ++fi)
        av[fi] = *(const bfx8*)(sA + ((wr << 6) + (fi << 4) + lr) * 128 + off);
#pragma unroll
      for (int fj = 0; fj < 4; ++fj)
        bv4[fj] = *(const bfx8*)(sB + ((wc << 6) + (fj << 4) + lr) * 128 + off);
#pragma unroll
      for (int fi = 0; fi < 4; ++fi)
#pragma unroll
        for (int fj = 0; fj < 4; ++fj)
          acc[fi][fj] = __builtin_amdgcn_mfma_f32_16x16x32_bf16(av[fi], bv4[fj], acc[fi][fj], 0, 0, 0);
    }
    __syncthreads();   // ds_writes + B gl_lds for tile kt+1 visible; buf kt free
  }
#undef ALOAD
#undef AWRITE
#undef BSTAGE

  // ---- epilogue ----
#pragma unroll
  for (int fj = 0; fj < 4; ++fj) {
    const int n = n0 + (wc << 6) + (fj << 4) + lr;
    const float bvl = bias[n];
#pragma unroll
    for (int fi = 0; fi < 4; ++fi) {
      if (z == 2) {
        const int h = n >> 6, d = n & 63;
        const int mm = m0 + (wr << 6) + (fi << 4) + (lg << 2);
        const int b = mm >> 11, s = mm & 2047;
        u16x4 pk4;
#pragma unroll
        for (int r = 0; r < 4; ++r) pk4[r] = f2bf(acc[fi][fj][r] + bvl);
        *(u16x4*)(vt + (size_t)(b * 16 + h) * 131072 + (size_t)d * 2048 + s) = pk4;
      } else {
#pragma unroll
        for (int r = 0; r < 4; ++r) {
          const int m = m0 + (wr << 6) + (fi << 4) + (lg << 2) + r;
          const float val = (acc[fi][fj][r] + bvl) * scale;
          const int b = m >> 11, s = m & 2047, h = n >> 6, d = n & 63;
          out0[(size_t)z * (8192ull * 1024) +
               (((size_t)(b * 16 + h) * 2048 + s) << 6) + d] = f2bf(val);
        }
      }
    }
  }
}

// ---------------- O-projection GEMM (bf16 A via gl_lds, 2-phase dbuf — proven) ----------------
__global__ void __launch_bounds__(256, 2)
gemm_o(const u16* __restrict__ A, const u16* __restrict__ Bt,
       const float* __restrict__ bias, float* __restrict__ out) {
  __shared__ __align__(16) char smem[65536];
  int m0, n0;
  xcd_remap(m0, n0);
  const int t = threadIdx.x;
  const int w = t >> 6, l = t & 63;
  const int lg = l >> 4, lr = l & 15;
  const int wr = w >> 1, wc = w & 1;

  f32x4 acc[4][4] = {};

  const int trow = t >> 3;
  const int scb = ((t & 7) << 4) ^ ((trow & 7) << 4);
  const char* gA = (const char*)A + (size_t)(m0 + trow) * 2048;
  const char* gB = (const char*)Bt + (size_t)(n0 + trow) * 2048;

#define GSTAGE(kt, buf)                                                        \
  do {                                                                         \
    _Pragma("unroll")                                                          \
    for (int i = 0; i < 4; ++i) {                                              \
      gl_lds16(gA + (size_t)i * 32 * 2048 + ((kt) << 7) + scb,                 \
               (buf) + (((i << 8) + (w << 6)) << 4));                          \
      gl_lds16(gB + (size_t)i * 32 * 2048 + ((kt) << 7) + scb,                 \
               (buf) + 16384 + (((i << 8) + (w << 6)) << 4));                  \
    }                                                                          \
  } while (0)

  GSTAGE(0, smem);
  __syncthreads();

  for (int kt = 0; kt < 16; ++kt) {
    char* sA = smem + ((kt & 1) << 15);
    char* sB = sA + 16384;
    if (kt < 15) GSTAGE(kt + 1, smem + (((kt + 1) & 1) << 15));

#pragma unroll
    for (int kk = 0; kk < 2; ++kk) {
      const int off = ((kk << 6) + (lg << 4)) ^ ((lr & 7) << 4);
      bfx8 av[4], bv4[4];
#pragma unroll
      for (int fi = 0; fi < 4; ++fi)
        av[fi] = *(const bfx8*)(sA + ((wr << 6) + (fi << 4) + lr) * 128 + off);
#pragma unroll
      for (int fj = 0; fj < 4; ++fj)
        bv4[fj] = *(const bfx8*)(sB + ((wc << 6) + (fj << 4) + lr) * 128 + off);
#pragma unroll
      for (int fi = 0; fi < 4; ++fi)
#pragma unroll
        for (int fj = 0; fj < 4; ++fj)
          acc[fi][fj] = __builtin_amdgcn_mfma_f32_16x16x32_bf16(av[fi], bv4[fj], acc[fi][fj], 0, 0, 0);
    }
    __syncthreads();
  }
#undef GSTAGE

#pragma unroll
  for (int fj = 0; fj < 4; ++fj) {
    const int n = n0 + (wc << 6) + (fj << 4) + lr;
    const float bvl = bias[n];
#pragma unroll
    for (int fi = 0; fi < 4; ++fi) {
#pragma unroll
      for (int r = 0; r < 4; ++r) {
        const int m = m0 + (wr << 6) + (fi << 4) + (lg << 2) + r;
        out[((size_t)m << 10) + n] = acc[fi][fj][r] + bvl;
      }
    }
  }
}

// ---------------- Flash attention (proven best: 76.6 µs) ----------------
// 32x32 MFMA, in-register P (cvt_pk + permlane32_swap), no-max softmax,
// 4 staging buffers, 2-tile super-iter, 512 thr = 8 waves x 32 q-rows.
__global__ void __launch_bounds__(512, 4)
attn_fwd(const u16* __restrict__ Qg, const u16* __restrict__ Kg,
         const u16* __restrict__ Vtg, u16* __restrict__ Og) {
  __shared__ __align__(16) char smem[65536];
  const int t = threadIdx.x;
  const int w = t >> 6, l = t & 63;
  const int l31 = l & 31, hi = l >> 5;

  const int id = blockIdx.x;               // 512 blocks
  const int xcd = id & 7, slot = id >> 3;  // slot 0..63
  const int pair = ((slot >> 3) << 3) + xcd;
  const int q0 = (slot & 7) << 8;

  const char* Qb = (const char*)Qg + ((size_t)pair << 18);
  const char* Kb = (const char*)Kg + ((size_t)pair << 18);
  const char* Vb = (const char*)Vtg + ((size_t)pair << 18);

  const int trow = t >> 3;
  const int scb = (((t & 7) ^ (trow & 7) ^ (((trow >> 3) & 3) << 1)) << 4);
  const int ldst = (w << 10);
  const int swz = (((l & 7) ^ ((l31 >> 3) << 1)) << 4);

  bfx8 qf[4];
#pragma unroll
  for (int ks = 0; ks < 4; ++ks)
    qf[ks] = *(const bfx8*)(Qb + (size_t)(q0 + (w << 5) + l31) * 128 + (ks << 5) + (hi << 4));

  f32x16 accO[2] = {};
  float Lp = 0.f;

#define ASTAGE(kt, buf)                                                         \
  do {                                                                          \
    gl_lds16(Kb + (size_t)(kt) * 8192 + (size_t)trow * 128 + scb, (buf) + ldst);\
    gl_lds16(Vb + (size_t)trow * 4096 + (size_t)(kt) * 128 + scb,               \
             (buf) + 8192 + ldst);                                              \
  } while (0)

  ASTAGE(0, smem);
  ASTAGE(1, smem + 16384);
  __syncthreads();

  for (int it2 = 0; it2 < 16; ++it2) {
    const int tt = it2 << 1;
    if (tt + 2 < 32) ASTAGE(tt + 2, smem + (((tt + 2) & 3) << 14));
    if (tt + 3 < 32) ASTAGE(tt + 3, smem + (((tt + 3) & 3) << 14));

#pragma unroll
    for (int u = 0; u < 2; ++u) {
      char* bK = smem + (((tt + u) & 3) << 14);
      char* bV = bK + 8192;

      f32x16 accS[2] = {{}, {}};
      __builtin_amdgcn_s_setprio(1);
#pragma unroll
      for (int mb = 0; mb < 2; ++mb) {
        bfx8 kf[4];
#pragma unroll
        for (int ks = 0; ks < 4; ++ks)
          kf[ks] = *(const bfx8*)(bK + (((mb << 5) + l31) << 7) + (((ks << 5) + (hi << 4)) ^ swz));
#pragma unroll
        for (int ks = 0; ks < 4; ++ks)
          accS[mb] = __builtin_amdgcn_mfma_f32_32x32x16_bf16(kf[ks], qf[ks], accS[mb], 0, 0, 0);
      }
      __builtin_amdgcn_s_setprio(0);

      bfx8 pa[4];
#pragma unroll
      for (int mb = 0; mb < 2; ++mb) {
#pragma unroll
        for (int r = 0; r < 16; ++r) {
          accS[mb][r] = __builtin_amdgcn_exp2f(accS[mb][r]);
          Lp += accS[mb][r];
        }
#pragma unroll
        for (int half = 0; half < 2; ++half) {
          u32 a0 = cvtpk(accS[mb][8 * half + 0], accS[mb][8 * half + 1]);
          u32 a1 = cvtpk(accS[mb][8 * half + 2], accS[mb][8 * half + 3]);
          u32 b0 = cvtpk(accS[mb][8 * half + 4], accS[mb][8 * half + 5]);
          u32 b1 = cvtpk(accS[mb][8 * half + 6], accS[mb][8 * half + 7]);
          asm volatile("v_permlane32_swap_b32 %0, %1" : "+v"(a0), "+v"(b0));
          asm volatile("v_permlane32_swap_b32 %0, %1" : "+v"(a1), "+v"(b1));
          u32x4 pk; pk[0] = a0; pk[1] = a1; pk[2] = b0; pk[3] = b1;
          pa[(mb << 1) + half] = *(bfx8*)&pk;
        }
      }

      __builtin_amdgcn_s_setprio(1);
#pragma unroll
      for (int ks = 0; ks < 4; ++ks) {
        bfx8 vf0 = *(const bfx8*)(bV + ((0 + l31) << 7) + (((ks << 5) + (hi << 4)) ^ swz));
        bfx8 vf1 = *(const bfx8*)(bV + ((32 + l31) << 7) + (((ks << 5) + (hi << 4)) ^ swz));
        accO[0] = __builtin_amdgcn_mfma_f32_32x32x16_bf16(pa[ks], vf0, accO[0], 0, 0, 0);
        accO[1] = __builtin_amdgcn_mfma_f32_32x32x16_bf16(pa[ks], vf1, accO[1], 0, 0, 0);
      }
      __builtin_amdgcn_s_setprio(0);
    }

    __syncthreads();
  }
#undef ASTAGE

  const float Ltot = Lp + __shfl_xor(Lp, 32);
  const int b = pair >> 4, h = pair & 15;
  u16* dstBase = Og + (((size_t)(b * 2048 + q0 + (w << 5))) << 10) + (h << 6) + l31;
#pragma unroll
  for (int r = 0; r < 16; ++r) {
    const int ql = (r & 3) + ((r >> 2) << 3) + (hi << 2);
    const float Lr = __shfl(Ltot, ql);
    const float rinv = __builtin_amdgcn_rcpf(Lr);
    u16* dst = dstBase + ((size_t)ql << 10);
    dst[0]  = f2bf(accO[0][r] * rinv);
    dst[32] = f2bf(accO[1][r] * rinv);
  }
}

extern "C" void kernel_launch(void* const* d_in, const int* in_sizes, int n_in,
                              void* d_out, int out_size, void* d_ws, size_t ws_size,
                              hipStream_t stream) {
  const float* q  = (const float*)d_in[0];
  const float* k  = (const float*)d_in[1];
  const float* v  = (const float*)d_in[2];
  const float* Wq = (const float*)d_in[3];
  const float* bq = (const float*)d_in[4];
  const float* Wk = (const float*)d_in[5];
  const float* bk = (const float*)d_in[6];
  const float* Wv = (const float*)d_in[7];
  const float* bv = (const float*)d_in[8];
  const float* Wo = (const float*)d_in[9];
  const float* bo = (const float*)d_in[10];
  float* out = (float*)d_out;
  char* ws = (char*)d_ws;

  const size_t MB = 1024 * 1024;
  if (ws_size < 104 * MB) return;

  u16* Ob  = (u16*)(ws + 0 * MB);    // attention output [8192][1024] bf16
  u16* wqt = (u16*)(ws + 48 * MB);   // [4x contiguous 2MB: Wq^T, Wk^T, Wv^T, Wo^T]
  u16* wot = (u16*)(ws + 54 * MB);
  u16* Qh  = (u16*)(ws + 56 * MB);   // Qh @56, Kh @72 (z-strided)
  u16* Kh  = (u16*)(ws + 72 * MB);
  u16* Vth = (u16*)(ws + 88 * MB);   // Vt[pair][64][2048] written directly by z==2

  wtrans4<<<dim3(16, 16, 4), 256, 0, stream>>>(Wq, Wk, Wv, Wo, wqt);
  gemm_qkvf<<<dim3(8, 64, 3), 256, 0, stream>>>(q, k, v, wqt, bq, bk, bv, Qh, Vth);
  attn_fwd<<<512, 512, 0, stream>>>(Qh, Kh, Vth, Ob);
  gemm_o<<<dim3(8, 64), 256, 0, stream>>>(Ob, wot, bo, out);
}